// Round 7
// baseline (85.811 us; speedup 1.0000x reference)
//
#include <hip/hip_runtime.h>
#include <math.h>

#define BB 2
#define PP 4096
#define HH 128
#define WW 128
#define KK 8
#define TS 8            // tile size in pixels (8x8 = 64 pixels = 1 wave)
#define NTX (WW / TS)   // 16
#define NTY (HH / TS)   // 16
#define NW 4            // waves per block (each handles PP/NW points)
#define SEG (PP / NW)   // 1024 points per wave segment
#define CIT (SEG / 64)  // 16 cull iterations per wave

typedef float vfloat4 __attribute__((ext_vector_type(4)));  // native vec for NT stores

// ---------------- K1: project all points once ----------------
__global__ __launch_bounds__(256) void project_kernel(
    const float* __restrict__ pw,     // [B,P,3]
    const float* __restrict__ Rm,     // [B,3,3]
    const float* __restrict__ Tv,     // [B,3]
    const float* __restrict__ fo,     // [B]
    float4* __restrict__ pts)         // [B*P] (x_ndc, y_ndc, z_view, unused)
{
    int t = blockIdx.x * blockDim.x + threadIdx.x;
    if (t >= BB * PP) return;
    int b = t >> 12;
    const float* r = Rm + b * 9;
    const float* q = pw + (size_t)t * 3;
    float x = q[0], y = q[1], z = q[2];
    // einsum order, rn ops to block FMA contraction (bit-match numpy)
    float vx = __fadd_rn(__fadd_rn(__fadd_rn(__fmul_rn(x, r[0]), __fmul_rn(y, r[3])), __fmul_rn(z, r[6])), Tv[b*3+0]);
    float vy = __fadd_rn(__fadd_rn(__fadd_rn(__fmul_rn(x, r[1]), __fmul_rn(y, r[4])), __fmul_rn(z, r[7])), Tv[b*3+1]);
    float vz = __fadd_rn(__fadd_rn(__fadd_rn(__fmul_rn(x, r[2]), __fmul_rn(y, r[5])), __fmul_rn(z, r[8])), Tv[b*3+2]);
    float f = fo[b];
    float xn = __fmul_rn(f, vx) / vz;
    float yn = __fmul_rn(f, vy) / vz;
    pts[t] = make_float4(xn, yn, vz, 0.0f);
}

// ---------------- K2: one block per 8x8 tile; cull from hot pts ----------------
__global__ __launch_bounds__(64 * NW, 2) void raster_kernel(
    const float4* __restrict__ pts,   // [B*P]
    float* __restrict__ out,          // idx | zbuf | dists planes, each N floats
    int N)
{
    __shared__ float4 cand[NW][SEG];  // 64 KB; reused as merge buffer later

    const int tx = blockIdx.x, ty = blockIdx.y, b = blockIdx.z;
    const int wv   = threadIdx.x >> 6;
    const int lane = threadIdx.x & 63;

    const float R2f   = (float)(0.05 * 0.05);
    const float apron = 0.05f + 1e-5f;  // conservative; exact d2<R^2 re-test inside

    // tile bbox in NDC (gx decreases with w, gy decreases with h)
    float gx_hi = 1.0f - 2.0f * ((float)(tx * TS)          + 0.5f) / (float)WW;
    float gx_lo = 1.0f - 2.0f * ((float)(tx * TS + TS - 1) + 0.5f) / (float)WW;
    float gy_hi = 1.0f - 2.0f * ((float)(ty * TS)          + 0.5f) / (float)HH;
    float gy_lo = 1.0f - 2.0f * ((float)(ty * TS + TS - 1) + 0.5f) / (float)HH;
    const float xmin = gx_lo - apron, xmax = gx_hi + apron;
    const float ymin = gy_lo - apron, ymax = gy_hi + apron;

    // ---- cull: prefetch whole segment as float4 (all loads in flight) ----
    const float4* pb = pts + (size_t)b * PP + wv * SEG + lane;
    float4 pf[CIT];
#pragma unroll
    for (int it = 0; it < CIT; ++it) pf[it] = pb[it * 64];

    int cnt = 0;
#pragma unroll
    for (int it = 0; it < CIT; ++it) {
        float4 q = pf[it];
        int i = wv * SEG + it * 64 + lane;
        bool keep = (q.z > 0.0f) && (q.x >= xmin) && (q.x <= xmax)
                                 && (q.y >= ymin) && (q.y <= ymax);
        unsigned long long m = __ballot(keep);
        if (keep) {
            int pos = __popcll(m & ((1ull << lane) - 1ull));
            cand[wv][cnt + pos] = make_float4(q.x, q.y, q.z, __int_as_float(i));
        }
        cnt += __popcll(m);           // wave-uniform
    }
    // intra-wave LDS RAW: in-order per wave — no barrier needed

    // ---- per-pixel top-K over this wave's candidates (LDS broadcast) ----
    int w = tx * TS + (lane & (TS - 1));
    int h = ty * TS + (lane / TS);
    float gx = 1.0f - 2.0f * ((float)w + 0.5f) / (float)WW;
    float gy = 1.0f - 2.0f * ((float)h + 0.5f) / (float)HH;

    float zk[KK], dk[KK]; int ik[KK];
#pragma unroll
    for (int j = 0; j < KK; ++j) { zk[j] = INFINITY; dk[j] = -1.0f; ik[j] = -1; }

    for (int s = 0; s < cnt; ++s) {
        float4 q = cand[wv][s];
        float dx = __fsub_rn(gx, q.x);
        float dy = __fsub_rn(gy, q.y);
        float d2 = __fadd_rn(__fmul_rn(dx, dx), __fmul_rn(dy, dy));
        float z = q.z;                 // z > 0 guaranteed by cull
        if (d2 < R2f && z < zk[KK - 1]) {
            int i = __float_as_int(q.w);
            // ascending index + strict '<' displacement == top_k tie-break
#pragma unroll
            for (int j = KK - 1; j >= 1; --j) {
                if (z < zk[j]) {
                    if (z < zk[j - 1]) { zk[j] = zk[j-1]; ik[j] = ik[j-1]; dk[j] = dk[j-1]; }
                    else               { zk[j] = z;       ik[j] = i;       dk[j] = d2;      }
                }
            }
            if (z < zk[0]) { zk[0] = z; ik[0] = i; dk[0] = d2; }
        }
    }

    // ---- publish per-wave lists (pixel-major => conflict-free merge reads) ----
    __syncthreads();
    float* mz = (float*)&cand[0][0];              // [NW][KK][64]
    float* mi = mz + NW * KK * 64;
    float* md = mi + NW * KK * 64;
#pragma unroll
    for (int s = 0; s < KK; ++s) {
        mz[(wv * KK + s) * 64 + lane] = zk[s];
        mi[(wv * KK + s) * 64 + lane] = __int_as_float(ik[s]);
        md[(wv * KK + s) * 64 + lane] = dk[s];
    }
    __syncthreads();

    if (wv == 0) {
        // 4-way merge of sorted (z, idx) lists for pixel 'lane'
        float hz[NW], hd[NW]; int hi_[NW], hp[NW];
#pragma unroll
        for (int wq = 0; wq < NW; ++wq) {
            hp[wq]  = 0;
            hz[wq]  = mz[(wq * KK) * 64 + lane];
            hi_[wq] = __float_as_int(mi[(wq * KK) * 64 + lane]);
            hd[wq]  = md[(wq * KK) * 64 + lane];
        }
        float A[KK], Z[KK], D[KK];
#pragma unroll
        for (int o = 0; o < KK; ++o) {
            int bw = 0;
#pragma unroll
            for (int wq = 1; wq < NW; ++wq) {
                bool better = (hz[wq] < hz[bw]) ||
                              ((hz[wq] == hz[bw]) && (hi_[wq] < hi_[bw]));
                if (better) bw = wq;
            }
            float sz = hz[0], sd = hd[0]; int si = hi_[0];
#pragma unroll
            for (int wq = 1; wq < NW; ++wq) {
                if (bw == wq) { sz = hz[wq]; sd = hd[wq]; si = hi_[wq]; }
            }
            A[o] = (float)si;
            Z[o] = (si >= 0) ? sz : -1.0f;
            D[o] = sd;                 // -1 for invalid by construction
#pragma unroll
            for (int wq = 0; wq < NW; ++wq) {
                if (bw == wq) {
                    int p = ++hp[wq];
                    if (p < KK) {
                        hz[wq]  = mz[(wq * KK + p) * 64 + lane];
                        hi_[wq] = __float_as_int(mi[(wq * KK + p) * 64 + lane]);
                        hd[wq]  = md[(wq * KK + p) * 64 + lane];
                    } else {
                        hz[wq] = INFINITY; hi_[wq] = -1; hd[wq] = -1.0f;
                    }
                }
            }
        }
        // ---- non-temporal output stores: no write-allocate, no RMW fetch ----
        int pix  = (b * HH + h) * WW + w;
        int base = pix * KK;           // 32B-aligned
        vfloat4* oa = (vfloat4*)(out + base);
        vfloat4* oz = (vfloat4*)(out + N + base);
        vfloat4* od = (vfloat4*)(out + 2 * N + base);
        __builtin_nontemporal_store(((vfloat4*)A)[0], oa);
        __builtin_nontemporal_store(((vfloat4*)A)[1], oa + 1);
        __builtin_nontemporal_store(((vfloat4*)Z)[0], oz);
        __builtin_nontemporal_store(((vfloat4*)Z)[1], oz + 1);
        __builtin_nontemporal_store(((vfloat4*)D)[0], od);
        __builtin_nontemporal_store(((vfloat4*)D)[1], od + 1);
    }
}

extern "C" void kernel_launch(void* const* d_in, const int* in_sizes, int n_in,
                              void* d_out, int out_size, void* d_ws, size_t ws_size,
                              hipStream_t stream) {
    const float* pw = (const float*)d_in[0];   // points_world [B,P,3]
    const float* Rm = (const float*)d_in[1];   // R [B,3,3]
    const float* Tv = (const float*)d_in[2];   // T [B,3]
    const float* fo = (const float*)d_in[3];   // focal [B]
    int N = out_size / 3;                      // B*H*W*K

    float4* pts = (float4*)d_ws;               // 128 KB scratch

    hipLaunchKernelGGL(project_kernel, dim3((BB * PP + 255) / 256), dim3(256), 0, stream,
                       pw, Rm, Tv, fo, pts);
    hipLaunchKernelGGL(raster_kernel, dim3(NTX, NTY, BB), dim3(64 * NW), 0, stream,
                       pts, (float*)d_out, N);
}

// Round 8
// 80.083 us; speedup vs baseline: 1.0715x; 1.0715x over previous
//
#include <hip/hip_runtime.h>
#include <math.h>

#define BB 2
#define PP 4096
#define HH 128
#define WW 128
#define KK 8
#define TS 8            // tile size in pixels (8x8 = 64 pixels)
#define NTX (WW / TS)   // 16
#define NTY (HH / TS)   // 16
#define NW 4            // waves per block (each handles PP/NW points)
#define SEG (PP / NW)   // 1024 points per wave segment

typedef float vfloat4 __attribute__((ext_vector_type(4)));  // native vec for NT stores

// One block = one 8x8 pixel tile. 4 waves split the point range; each wave
// projects+culls its segment into LDS (ballot compaction), builds a per-pixel
// sorted top-8; the 4 sorted lists are merged per pixel, 16 pixels per wave.
__global__ __launch_bounds__(64 * NW, 2) void raster_kernel(
    const float* __restrict__ pw,     // [B,P,3]
    const float* __restrict__ Rm,     // [B,3,3]
    const float* __restrict__ Tv,     // [B,3]
    const float* __restrict__ fo,     // [B]
    float* __restrict__ out,          // idx | zbuf | dists planes, each N floats
    int N)
{
    __shared__ float4 cand[NW][SEG];  // 64 KB; reused as merge buffer later

    const int tx = blockIdx.x, ty = blockIdx.y, b = blockIdx.z;
    const int wv   = threadIdx.x >> 6;   // wave id 0..3
    const int lane = threadIdx.x & 63;

    // ---- uniform camera params (scalar loads) ----
    const float* r = Rm + b * 9;
    const float r00=r[0], r01=r[1], r02=r[2];
    const float r10=r[3], r11=r[4], r12=r[5];
    const float r20=r[6], r21=r[7], r22=r[8];
    const float t0=Tv[b*3+0], t1=Tv[b*3+1], t2=Tv[b*3+2];
    const float f = fo[b];

    const float R2f   = (float)(0.05 * 0.05);
    const float apron = 0.05f + 1e-5f;  // conservative; exact d2<R^2 re-test inside

    // tile bbox in NDC (gx decreases with w, gy decreases with h)
    float gx_hi = 1.0f - 2.0f * ((float)(tx * TS)          + 0.5f) / (float)WW;
    float gx_lo = 1.0f - 2.0f * ((float)(tx * TS + TS - 1) + 0.5f) / (float)WW;
    float gy_hi = 1.0f - 2.0f * ((float)(ty * TS)          + 0.5f) / (float)HH;
    float gy_lo = 1.0f - 2.0f * ((float)(ty * TS + TS - 1) + 0.5f) / (float)HH;
    const float xmin = gx_lo - apron, xmax = gx_hi + apron;
    const float ymin = gy_lo - apron, ymax = gy_hi + apron;

    // ---- fused project + cull into LDS (depth-1 pipelined, per-wave segment) ----
    int cnt = 0;
    const float* pwb = pw + (size_t)b * PP * 3;
    const float* qp = pwb + (wv * SEG + lane) * 3;
    float cx = qp[0], cy = qp[1], cz = qp[2];
    for (int it = 0; it < SEG / 64; ++it) {
        float nx = 0.f, ny = 0.f, nz = 0.f;
        if (it + 1 < SEG / 64) {
            const float* qn = qp + (it + 1) * 192;   // 64 lanes * 3 floats
            nx = qn[0]; ny = qn[1]; nz = qn[2];
        }
        int i = wv * SEG + it * 64 + lane;
        float x = cx, y = cy, z = cz;
        // einsum order, rn ops to block FMA contraction (match numpy exactly)
        float vx = __fadd_rn(__fadd_rn(__fadd_rn(__fmul_rn(x, r00), __fmul_rn(y, r10)), __fmul_rn(z, r20)), t0);
        float vy = __fadd_rn(__fadd_rn(__fadd_rn(__fmul_rn(x, r01), __fmul_rn(y, r11)), __fmul_rn(z, r21)), t1);
        float vz = __fadd_rn(__fadd_rn(__fadd_rn(__fmul_rn(x, r02), __fmul_rn(y, r12)), __fmul_rn(z, r22)), t2);
        float xn = __fmul_rn(f, vx) / vz;
        float yn = __fmul_rn(f, vy) / vz;
        bool keep = (vz > 0.0f) && (xn >= xmin) && (xn <= xmax)
                                && (yn >= ymin) && (yn <= ymax);
        unsigned long long m = __ballot(keep);
        if (keep) {
            int pos = __popcll(m & ((1ull << lane) - 1ull));
            cand[wv][cnt + pos] = make_float4(xn, yn, vz, __int_as_float(i));
        }
        cnt += __popcll(m);           // wave-uniform
        cx = nx; cy = ny; cz = nz;
    }
    // intra-wave LDS RAW: in-order per wave — no barrier needed

    // ---- per-pixel top-K, 4-ahead LDS staging (breaks latency chain) ----
    int w = tx * TS + (lane & (TS - 1));
    int h = ty * TS + (lane / TS);
    float gx = 1.0f - 2.0f * ((float)w + 0.5f) / (float)WW;
    float gy = 1.0f - 2.0f * ((float)h + 0.5f) / (float)HH;

    float zk[KK], dk[KK]; int ik[KK];
#pragma unroll
    for (int j = 0; j < KK; ++j) { zk[j] = INFINITY; dk[j] = -1.0f; ik[j] = -1; }

    // exact R6 insert semantics: ascending s order + strict '<' == top_k tie-break
    auto proc = [&](float4 q) {
        float dx = __fsub_rn(gx, q.x);
        float dy = __fsub_rn(gy, q.y);
        float d2 = __fadd_rn(__fmul_rn(dx, dx), __fmul_rn(dy, dy));
        float z = q.z;                 // z > 0 guaranteed by cull
        if (d2 < R2f && z < zk[KK - 1]) {
            int i = __float_as_int(q.w);
#pragma unroll
            for (int j = KK - 1; j >= 1; --j) {
                if (z < zk[j]) {
                    if (z < zk[j - 1]) { zk[j] = zk[j-1]; ik[j] = ik[j-1]; dk[j] = dk[j-1]; }
                    else               { zk[j] = z;       ik[j] = i;       dk[j] = d2;      }
                }
            }
            if (z < zk[0]) { zk[0] = z; ik[0] = i; dk[0] = d2; }
        }
    };

    int s = 0;
    for (; s + 4 <= cnt; s += 4) {
        float4 q0 = cand[wv][s];       // 4 independent ds_read_b128 in flight
        float4 q1 = cand[wv][s + 1];
        float4 q2 = cand[wv][s + 2];
        float4 q3 = cand[wv][s + 3];
        proc(q0); proc(q1); proc(q2); proc(q3);
    }
    for (; s < cnt; ++s) proc(cand[wv][s]);

    // ---- publish per-wave lists (pixel-major => conflict-free merge reads) ----
    __syncthreads();                  // all waves done reading cand
    float* mz = (float*)&cand[0][0];              // [NW][KK][64]
    float* mi = mz + NW * KK * 64;
    float* md = mi + NW * KK * 64;
#pragma unroll
    for (int sj = 0; sj < KK; ++sj) {
        mz[(wv * KK + sj) * 64 + lane] = zk[sj];
        mi[(wv * KK + sj) * 64 + lane] = __int_as_float(ik[sj]);
        md[(wv * KK + sj) * 64 + lane] = dk[sj];
    }
    __syncthreads();

    // ---- 4-way merge, distributed: each wave handles 16 pixels (lanes 0-15) ----
    if (lane < 16) {
        const int pe = wv * 16 + lane;           // pixel id within tile
        float hz[NW], hd[NW]; int hi_[NW], hp[NW];
#pragma unroll
        for (int wq = 0; wq < NW; ++wq) {
            hp[wq]  = 0;
            hz[wq]  = mz[(wq * KK) * 64 + pe];
            hi_[wq] = __float_as_int(mi[(wq * KK) * 64 + pe]);
            hd[wq]  = md[(wq * KK) * 64 + pe];
        }
        float A[KK], Z[KK], D[KK];
#pragma unroll
        for (int o = 0; o < KK; ++o) {
            int bw = 0;
#pragma unroll
            for (int wq = 1; wq < NW; ++wq) {
                bool better = (hz[wq] < hz[bw]) ||
                              ((hz[wq] == hz[bw]) && (hi_[wq] < hi_[bw]));
                if (better) bw = wq;
            }
            float sz = hz[0], sd = hd[0]; int si = hi_[0];
#pragma unroll
            for (int wq = 1; wq < NW; ++wq) {
                if (bw == wq) { sz = hz[wq]; sd = hd[wq]; si = hi_[wq]; }
            }
            A[o] = (float)si;
            Z[o] = (si >= 0) ? sz : -1.0f;
            D[o] = sd;                 // -1 for invalid by construction
#pragma unroll
            for (int wq = 0; wq < NW; ++wq) {
                if (bw == wq) {
                    int p = ++hp[wq];
                    if (p < KK) {
                        hz[wq]  = mz[(wq * KK + p) * 64 + pe];
                        hi_[wq] = __float_as_int(mi[(wq * KK + p) * 64 + pe]);
                        hd[wq]  = md[(wq * KK + p) * 64 + pe];
                    } else {
                        hz[wq] = INFINITY; hi_[wq] = -1; hd[wq] = -1.0f;
                    }
                }
            }
        }
        // ---- non-temporal output stores: no write-allocate, no RMW fetch ----
        int w2 = tx * TS + (pe & (TS - 1));
        int h2 = ty * TS + (pe / TS);
        int pix  = (b * HH + h2) * WW + w2;
        int base = pix * KK;           // 32B-aligned
        vfloat4* oa = (vfloat4*)(out + base);
        vfloat4* oz = (vfloat4*)(out + N + base);
        vfloat4* od = (vfloat4*)(out + 2 * N + base);
        __builtin_nontemporal_store(((vfloat4*)A)[0], oa);
        __builtin_nontemporal_store(((vfloat4*)A)[1], oa + 1);
        __builtin_nontemporal_store(((vfloat4*)Z)[0], oz);
        __builtin_nontemporal_store(((vfloat4*)Z)[1], oz + 1);
        __builtin_nontemporal_store(((vfloat4*)D)[0], od);
        __builtin_nontemporal_store(((vfloat4*)D)[1], od + 1);
    }
}

extern "C" void kernel_launch(void* const* d_in, const int* in_sizes, int n_in,
                              void* d_out, int out_size, void* d_ws, size_t ws_size,
                              hipStream_t stream) {
    const float* pw = (const float*)d_in[0];   // points_world [B,P,3]
    const float* Rm = (const float*)d_in[1];   // R [B,3,3]
    const float* Tv = (const float*)d_in[2];   // T [B,3]
    const float* fo = (const float*)d_in[3];   // focal [B]
    int N = out_size / 3;                      // B*H*W*K

    hipLaunchKernelGGL(raster_kernel, dim3(NTX, NTY, BB), dim3(64 * NW), 0, stream,
                       pw, Rm, Tv, fo, (float*)d_out, N);
}

// Round 9
// 79.081 us; speedup vs baseline: 1.0851x; 1.0127x over previous
//
#include <hip/hip_runtime.h>
#include <math.h>

#define BB 2
#define PP 4096
#define HH 128
#define WW 128
#define KK 8
#define TS 8            // tile size in pixels (8x8 = 64 pixels)
#define NTX (WW / TS)   // 16
#define NTY (HH / TS)   // 16
#define NW 4            // waves per block (each handles PP/NW points)
#define SEG (PP / NW)   // 1024 points per wave segment

// One block = one 8x8 pixel tile. 4 waves split the point range; each wave
// projects+culls its segment into LDS (ballot compaction), builds a per-pixel
// sorted top-8; the 4 sorted lists are merged per pixel, 16 pixels per wave.
// R9 = R8 with PLAIN stores (A/B test: NT stores vs dirty-poison L2 lines).
__global__ __launch_bounds__(64 * NW, 2) void raster_kernel(
    const float* __restrict__ pw,     // [B,P,3]
    const float* __restrict__ Rm,     // [B,3,3]
    const float* __restrict__ Tv,     // [B,3]
    const float* __restrict__ fo,     // [B]
    float* __restrict__ out,          // idx | zbuf | dists planes, each N floats
    int N)
{
    __shared__ float4 cand[NW][SEG];  // 64 KB; reused as merge buffer later

    const int tx = blockIdx.x, ty = blockIdx.y, b = blockIdx.z;
    const int wv   = threadIdx.x >> 6;   // wave id 0..3
    const int lane = threadIdx.x & 63;

    // ---- uniform camera params (scalar loads) ----
    const float* r = Rm + b * 9;
    const float r00=r[0], r01=r[1], r02=r[2];
    const float r10=r[3], r11=r[4], r12=r[5];
    const float r20=r[6], r21=r[7], r22=r[8];
    const float t0=Tv[b*3+0], t1=Tv[b*3+1], t2=Tv[b*3+2];
    const float f = fo[b];

    const float R2f   = (float)(0.05 * 0.05);
    const float apron = 0.05f + 1e-5f;  // conservative; exact d2<R^2 re-test inside

    // tile bbox in NDC (gx decreases with w, gy decreases with h)
    float gx_hi = 1.0f - 2.0f * ((float)(tx * TS)          + 0.5f) / (float)WW;
    float gx_lo = 1.0f - 2.0f * ((float)(tx * TS + TS - 1) + 0.5f) / (float)WW;
    float gy_hi = 1.0f - 2.0f * ((float)(ty * TS)          + 0.5f) / (float)HH;
    float gy_lo = 1.0f - 2.0f * ((float)(ty * TS + TS - 1) + 0.5f) / (float)HH;
    const float xmin = gx_lo - apron, xmax = gx_hi + apron;
    const float ymin = gy_lo - apron, ymax = gy_hi + apron;

    // ---- fused project + cull into LDS (depth-1 pipelined, per-wave segment) ----
    int cnt = 0;
    const float* pwb = pw + (size_t)b * PP * 3;
    const float* qp = pwb + (wv * SEG + lane) * 3;
    float cx = qp[0], cy = qp[1], cz = qp[2];
    for (int it = 0; it < SEG / 64; ++it) {
        float nx = 0.f, ny = 0.f, nz = 0.f;
        if (it + 1 < SEG / 64) {
            const float* qn = qp + (it + 1) * 192;   // 64 lanes * 3 floats
            nx = qn[0]; ny = qn[1]; nz = qn[2];
        }
        int i = wv * SEG + it * 64 + lane;
        float x = cx, y = cy, z = cz;
        // einsum order, rn ops to block FMA contraction (match numpy exactly)
        float vx = __fadd_rn(__fadd_rn(__fadd_rn(__fmul_rn(x, r00), __fmul_rn(y, r10)), __fmul_rn(z, r20)), t0);
        float vy = __fadd_rn(__fadd_rn(__fadd_rn(__fmul_rn(x, r01), __fmul_rn(y, r11)), __fmul_rn(z, r21)), t1);
        float vz = __fadd_rn(__fadd_rn(__fadd_rn(__fmul_rn(x, r02), __fmul_rn(y, r12)), __fmul_rn(z, r22)), t2);
        float xn = __fmul_rn(f, vx) / vz;
        float yn = __fmul_rn(f, vy) / vz;
        bool keep = (vz > 0.0f) && (xn >= xmin) && (xn <= xmax)
                                && (yn >= ymin) && (yn <= ymax);
        unsigned long long m = __ballot(keep);
        if (keep) {
            int pos = __popcll(m & ((1ull << lane) - 1ull));
            cand[wv][cnt + pos] = make_float4(xn, yn, vz, __int_as_float(i));
        }
        cnt += __popcll(m);           // wave-uniform
        cx = nx; cy = ny; cz = nz;
    }
    // intra-wave LDS RAW: in-order per wave — no barrier needed

    // ---- per-pixel top-K, 4-ahead LDS staging (breaks latency chain) ----
    int w = tx * TS + (lane & (TS - 1));
    int h = ty * TS + (lane / TS);
    float gx = 1.0f - 2.0f * ((float)w + 0.5f) / (float)WW;
    float gy = 1.0f - 2.0f * ((float)h + 0.5f) / (float)HH;

    float zk[KK], dk[KK]; int ik[KK];
#pragma unroll
    for (int j = 0; j < KK; ++j) { zk[j] = INFINITY; dk[j] = -1.0f; ik[j] = -1; }

    // exact R6 insert semantics: ascending s order + strict '<' == top_k tie-break
    auto proc = [&](float4 q) {
        float dx = __fsub_rn(gx, q.x);
        float dy = __fsub_rn(gy, q.y);
        float d2 = __fadd_rn(__fmul_rn(dx, dx), __fmul_rn(dy, dy));
        float z = q.z;                 // z > 0 guaranteed by cull
        if (d2 < R2f && z < zk[KK - 1]) {
            int i = __float_as_int(q.w);
#pragma unroll
            for (int j = KK - 1; j >= 1; --j) {
                if (z < zk[j]) {
                    if (z < zk[j - 1]) { zk[j] = zk[j-1]; ik[j] = ik[j-1]; dk[j] = dk[j-1]; }
                    else               { zk[j] = z;       ik[j] = i;       dk[j] = d2;      }
                }
            }
            if (z < zk[0]) { zk[0] = z; ik[0] = i; dk[0] = d2; }
        }
    };

    int s = 0;
    for (; s + 4 <= cnt; s += 4) {
        float4 q0 = cand[wv][s];       // 4 independent ds_read_b128 in flight
        float4 q1 = cand[wv][s + 1];
        float4 q2 = cand[wv][s + 2];
        float4 q3 = cand[wv][s + 3];
        proc(q0); proc(q1); proc(q2); proc(q3);
    }
    for (; s < cnt; ++s) proc(cand[wv][s]);

    // ---- publish per-wave lists (pixel-major => conflict-free merge reads) ----
    __syncthreads();                  // all waves done reading cand
    float* mz = (float*)&cand[0][0];              // [NW][KK][64]
    float* mi = mz + NW * KK * 64;
    float* md = mi + NW * KK * 64;
#pragma unroll
    for (int sj = 0; sj < KK; ++sj) {
        mz[(wv * KK + sj) * 64 + lane] = zk[sj];
        mi[(wv * KK + sj) * 64 + lane] = __int_as_float(ik[sj]);
        md[(wv * KK + sj) * 64 + lane] = dk[sj];
    }
    __syncthreads();

    // ---- 4-way merge, distributed: each wave handles 16 pixels (lanes 0-15) ----
    if (lane < 16) {
        const int pe = wv * 16 + lane;           // pixel id within tile
        float hz[NW], hd[NW]; int hi_[NW], hp[NW];
#pragma unroll
        for (int wq = 0; wq < NW; ++wq) {
            hp[wq]  = 0;
            hz[wq]  = mz[(wq * KK) * 64 + pe];
            hi_[wq] = __float_as_int(mi[(wq * KK) * 64 + pe]);
            hd[wq]  = md[(wq * KK) * 64 + pe];
        }
        float A[KK], Z[KK], D[KK];
#pragma unroll
        for (int o = 0; o < KK; ++o) {
            int bw = 0;
#pragma unroll
            for (int wq = 1; wq < NW; ++wq) {
                bool better = (hz[wq] < hz[bw]) ||
                              ((hz[wq] == hz[bw]) && (hi_[wq] < hi_[bw]));
                if (better) bw = wq;
            }
            float sz = hz[0], sd = hd[0]; int si = hi_[0];
#pragma unroll
            for (int wq = 1; wq < NW; ++wq) {
                if (bw == wq) { sz = hz[wq]; sd = hd[wq]; si = hi_[wq]; }
            }
            A[o] = (float)si;
            Z[o] = (si >= 0) ? sz : -1.0f;
            D[o] = sd;                 // -1 for invalid by construction
#pragma unroll
            for (int wq = 0; wq < NW; ++wq) {
                if (bw == wq) {
                    int p = ++hp[wq];
                    if (p < KK) {
                        hz[wq]  = mz[(wq * KK + p) * 64 + pe];
                        hi_[wq] = __float_as_int(mi[(wq * KK + p) * 64 + pe]);
                        hd[wq]  = md[(wq * KK + p) * 64 + pe];
                    } else {
                        hz[wq] = INFINITY; hi_[wq] = -1; hd[wq] = -1.0f;
                    }
                }
            }
        }
        // ---- plain stores (A/B vs NT): poison-dirty L2 lines absorb these ----
        int w2 = tx * TS + (pe & (TS - 1));
        int h2 = ty * TS + (pe / TS);
        int pix  = (b * HH + h2) * WW + w2;
        int base = pix * KK;           // 32B-aligned
        float4* oa = (float4*)(out + base);
        float4* oz = (float4*)(out + N + base);
        float4* od = (float4*)(out + 2 * N + base);
        oa[0] = ((float4*)A)[0]; oa[1] = ((float4*)A)[1];
        oz[0] = ((float4*)Z)[0]; oz[1] = ((float4*)Z)[1];
        od[0] = ((float4*)D)[0]; od[1] = ((float4*)D)[1];
    }
}

extern "C" void kernel_launch(void* const* d_in, const int* in_sizes, int n_in,
                              void* d_out, int out_size, void* d_ws, size_t ws_size,
                              hipStream_t stream) {
    const float* pw = (const float*)d_in[0];   // points_world [B,P,3]
    const float* Rm = (const float*)d_in[1];   // R [B,3,3]
    const float* Tv = (const float*)d_in[2];   // T [B,3]
    const float* fo = (const float*)d_in[3];   // focal [B]
    int N = out_size / 3;                      // B*H*W*K

    hipLaunchKernelGGL(raster_kernel, dim3(NTX, NTY, BB), dim3(64 * NW), 0, stream,
                       pw, Rm, Tv, fo, (float*)d_out, N);
}